// Round 5
// baseline (824.579 us; speedup 1.0000x reference)
//
#include <hip/hip_runtime.h>
#include <stdint.h>

__device__ __forceinline__ uint32_t pack4f(float4 f) {
  int x = (int)f.x, y = (int)f.y, z = (int)f.z, w = (int)f.w;
  x = min(max(x, 0), 255); y = min(max(y, 0), 255);
  z = min(max(z, 0), 255); w = min(max(w, 0), 255);
  return (uint32_t)x | ((uint32_t)y << 8) | ((uint32_t)z << 16) | ((uint32_t)w << 24);
}

__device__ __forceinline__ uint32_t qword(const uint4& v, int q) {
  return q == 0 ? v.x : q == 1 ? v.y : q == 2 ? v.z : v.w;
}

// 256x256 int32 LUT -> u8 linear
__global__ __launch_bounds__(256) void pack_lut_k(const int* __restrict__ lut,
                                                  uint8_t* __restrict__ out, int n16) {
  int t = blockIdx.x * 256 + threadIdx.x;
  if (t >= n16) return;
  const int4* s = (const int4*)lut;
  uint32_t w[4];
#pragma unroll
  for (int q = 0; q < 4; q++) {
    int4 v = s[t * 4 + q];
    w[q] = (uint32_t)(v.x & 255) | ((uint32_t)(v.y & 255) << 8) |
           ((uint32_t)(v.z & 255) << 16) | ((uint32_t)(v.w & 255) << 24);
  }
  ((uint4*)out)[t] = make_uint4(w[0], w[1], w[2], w[3]);
}

// [R][K] f32 codes -> u8 codes, same layout (used for weight -> W8[N][K])
__global__ __launch_bounds__(256) void pack_lin_k(const float* __restrict__ a,
                                                  uint8_t* __restrict__ out, int n16) {
  int t = blockIdx.x * 256 + threadIdx.x;
  if (t >= n16) return;
  const float4* s = (const float4*)a;
  uint32_t w[4];
#pragma unroll
  for (int q = 0; q < 4; q++) w[q] = pack4f(s[t * 4 + q]);
  ((uint4*)out)[t] = make_uint4(w[0], w[1], w[2], w[3]);
}

// [R][K] f32 -> chunk-transposed [K/16][R][16] u8 (used for input -> At)
__global__ __launch_bounds__(256) void pack_tr_k(const float* __restrict__ w,
                                                 uint8_t* __restrict__ out, int R, int K) {
  int t = blockIdx.x * 256 + threadIdx.x;
  int cpk = K >> 4;
  if (t >= R * cpk) return;
  int n = t / cpk, c = t - n * cpk;
  const float4* s = (const float4*)(w + (size_t)n * K + (size_t)c * 16);
  uint32_t x0 = pack4f(s[0]), x1 = pack4f(s[1]), x2 = pack4f(s[2]), x3 = pack4f(s[3]);
  *(uint4*)(out + ((size_t)c * R + n) * 16) = make_uint4(x0, x1, x2, x3);
}

// Main: lane owns a ROW (a per-lane, consecutive), w wave-uniform per gather.
// LUT stored XOR-swizzled: byte (a,w) at (a<<8) | (w ^ ((a&31)<<2)).
// Load bank = (w>>2) ^ (a&31): each 32-lane phase covers all 32 banks exactly
// once -> deterministically zero LDS conflicts, 2 cyc per wave-gather.
__global__ __launch_bounds__(512, 4) void lutmm_rowlane(
    const uint8_t* __restrict__ At,   // [K/16][M][16] u8
    const uint8_t* __restrict__ W8,   // [N][K] u8
    const uint8_t* __restrict__ LUT8, // [256][256] u8 linear
    const float* __restrict__ bias,
    float* __restrict__ out, int M, int N, int K) {
  __shared__ uint8_t lut[65536];
  {
    const uint32_t* s = (const uint32_t*)LUT8;
    uint32_t* d = (uint32_t*)lut;
#pragma unroll
    for (int it = 0; it < 32; it++) {
      int i = threadIdx.x + it * 512;
      uint32_t a = (uint32_t)i >> 6, w4 = (uint32_t)i & 63u;
      d[(a << 6) | (w4 ^ (a & 31u))] = s[i];
    }
  }
  __syncthreads();

  const int lane = threadIdx.x & 63;
  const int wid = threadIdx.x >> 6;
  const int row = blockIdx.y * 64 + lane;        // lane owns this output row
  const int cbase = blockIdx.x * 64 + wid * 8;   // wave owns 8 consecutive cols
  uint32_t acc[8] = {};

  for (int kb = 0; kb < K; kb += 16) {
    uint4 av = *(const uint4*)(At + ((size_t)(kb >> 4) * M + row) * 16);  // coalesced
    uint4 wv[8];
#pragma unroll
    for (int j = 0; j < 8; j++)  // wave-uniform broadcasts
      wv[j] = *(const uint4*)(W8 + (size_t)(cbase + j) * K + kb);
#pragma unroll
    for (int q = 0; q < 4; q++) {
      uint32_t aw = qword(av, q);
#pragma unroll
      for (int b = 0; b < 4; b++) {
        uint32_t a = (aw >> (b * 8)) & 255u;
        uint32_t key = (a << 8) | ((a & 31u) << 2);   // row base | xor-swizzle key
#pragma unroll
        for (int j = 0; j < 8; j++) {
          uint32_t wb = (qword(wv[j], q) >> (b * 8)) & 255u;
          acc[j] += lut[wb ^ key];
        }
      }
    }
  }

#pragma unroll
  for (int j = 0; j < 8; j++) {
    int c = cbase + j;
    out[(size_t)row * N + c] = (float)acc[j] + bias[c];
  }
}

// Fallback if ws too small: read f32 codes directly (R1-proven structure).
__global__ __launch_bounds__(1024, 8) void lutmm_f32(
    const float* __restrict__ A, const float* __restrict__ W,
    const int* __restrict__ LUT32, const float* __restrict__ bias,
    float* __restrict__ out, int M, int N, int K) {
  __shared__ uint8_t lut[65536];
  for (int i = threadIdx.x; i < 16384; i += 1024) {
    int4 v = ((const int4*)LUT32)[i];
    ((uint32_t*)lut)[i] = (uint32_t)(v.x & 255) | ((uint32_t)(v.y & 255) << 8) |
                          ((uint32_t)(v.z & 255) << 16) | ((uint32_t)(v.w & 255) << 24);
  }
  __syncthreads();

  const int lane = threadIdx.x & 63;
  const int wid = threadIdx.x >> 6;
  const int r0 = blockIdx.y * 16 + wid;
  const int cbase = blockIdx.x * 256 + lane;
  uint32_t acc[4] = {};

  for (int kb = 0; kb < K; kb += 16) {
    const float4* sa = (const float4*)(A + (size_t)r0 * K + kb);
    uint4 ap = make_uint4(pack4f(sa[0]), pack4f(sa[1]), pack4f(sa[2]), pack4f(sa[3]));
    uint4 wp[4];
#pragma unroll
    for (int j = 0; j < 4; j++) {
      const float4* s = (const float4*)(W + (size_t)(cbase + j * 64) * K + kb);
      wp[j] = make_uint4(pack4f(s[0]), pack4f(s[1]), pack4f(s[2]), pack4f(s[3]));
    }
#pragma unroll
    for (int q = 0; q < 4; q++)
#pragma unroll
      for (int b = 0; b < 4; b++) {
        uint32_t as = ((qword(ap, q) >> (b * 8)) & 255u) << 8;
#pragma unroll
        for (int j = 0; j < 4; j++)
          acc[j] += lut[as | ((qword(wp[j], q) >> (b * 8)) & 255u)];
      }
  }

#pragma unroll
  for (int j = 0; j < 4; j++) {
    int c = cbase + j * 64;
    out[(size_t)r0 * N + c] = (float)acc[j] + bias[c];
  }
}

extern "C" void kernel_launch(void* const* d_in, const int* in_sizes, int n_in,
                              void* d_out, int out_size, void* d_ws, size_t ws_size,
                              hipStream_t stream) {
  const float* inp  = (const float*)d_in[0];  // [M][K]
  const float* wgt  = (const float*)d_in[1];  // [N][K]
  const float* bias = (const float*)d_in[2];  // [N]
  const int*   lut  = (const int*)d_in[3];    // [256][256]

  const int N = in_sizes[2];
  const int K = in_sizes[1] / N;
  const int M = in_sizes[0] / K;
  float* out = (float*)d_out;

  size_t need = 65536 + (size_t)M * K + (size_t)N * K;

  if (ws_size >= need) {
    uint8_t* lut8 = (uint8_t*)d_ws;
    uint8_t* at8  = lut8 + 65536;           // [K/16][M][16]
    uint8_t* w8   = at8 + (size_t)M * K;    // [N][K]
    pack_lut_k<<<16, 256, 0, stream>>>(lut, lut8, 65536 / 16);
    int an16 = (M * K) / 16;
    pack_tr_k<<<(an16 + 255) / 256, 256, 0, stream>>>(inp, at8, M, K);
    int wn16 = (N * K) / 16;
    pack_lin_k<<<(wn16 + 255) / 256, 256, 0, stream>>>(wgt, w8, wn16);
    dim3 grid(N / 64, M / 64);
    lutmm_rowlane<<<grid, 512, 0, stream>>>(at8, w8, lut8, bias, out, M, N, K);
  } else {
    dim3 grid(N / 256, M / 16);
    lutmm_f32<<<grid, 1024, 0, stream>>>(inp, wgt, lut, bias, out, M, N, K);
  }
}

// Round 9
// 323.998 us; speedup vs baseline: 2.5450x; 2.5450x over previous
//
#include <hip/hip_runtime.h>
#include <stdint.h>

#define KSPLIT 8

__device__ __forceinline__ uint32_t pack4f(float4 f) {
  int x = (int)f.x, y = (int)f.y, z = (int)f.z, w = (int)f.w;
  x = min(max(x, 0), 255); y = min(max(y, 0), 255);
  z = min(max(z, 0), 255); w = min(max(w, 0), 255);
  return (uint32_t)x | ((uint32_t)y << 8) | ((uint32_t)z << 16) | ((uint32_t)w << 24);
}

// clip + swizzle code w -> w' = (w>>2) | ((w&3)<<6)  (T-table gather index)
__device__ __forceinline__ uint32_t pack4f_swz(float4 f) {
  float vv[4] = {f.x, f.y, f.z, f.w};
  uint32_t r = 0;
#pragma unroll
  for (int i = 0; i < 4; i++) {
    uint32_t w = (uint32_t)min(max((int)vv[i], 0), 255);
    w = (w >> 2) | ((w & 3u) << 6);
    r |= w << (8 * i);
  }
  return r;
}

__device__ __forceinline__ uint32_t qword(const uint4& v, int q) {
  return q == 0 ? v.x : q == 1 ? v.y : q == 2 ? v.z : v.w;
}

// 256x256 int32 LUT -> u8 linear
__global__ __launch_bounds__(256) void pack_lut_k(const int* __restrict__ lut,
                                                  uint8_t* __restrict__ out, int n16) {
  int t = blockIdx.x * 256 + threadIdx.x;
  if (t >= n16) return;
  const int4* s = (const int4*)lut;
  uint32_t w[4];
#pragma unroll
  for (int q = 0; q < 4; q++) {
    int4 v = s[t * 4 + q];
    w[q] = (uint32_t)(v.x & 255) | ((uint32_t)(v.y & 255) << 8) |
           ((uint32_t)(v.z & 255) << 16) | ((uint32_t)(v.w & 255) << 24);
  }
  ((uint4*)out)[t] = make_uint4(w[0], w[1], w[2], w[3]);
}

// input [M][K] f32 codes -> u8 codes, same layout
__global__ __launch_bounds__(256) void pack_lin_k(const float* __restrict__ a,
                                                  uint8_t* __restrict__ out, int n16) {
  int t = blockIdx.x * 256 + threadIdx.x;
  if (t >= n16) return;
  const float4* s = (const float4*)a;
  uint32_t w[4];
#pragma unroll
  for (int q = 0; q < 4; q++) w[q] = pack4f(s[t * 4 + q]);
  ((uint4*)out)[t] = make_uint4(w[0], w[1], w[2], w[3]);
}

// weight [N][K] f32 -> chunk-transposed [K/16][N][16] u8 with SWIZZLED codes
__global__ __launch_bounds__(256) void pack_wt_swz_k(const float* __restrict__ w,
                                                     uint8_t* __restrict__ out, int N, int K) {
  int t = blockIdx.x * 256 + threadIdx.x;
  int cpk = K >> 4;
  if (t >= N * cpk) return;
  int n = t / cpk, c = t - n * cpk;
  const float4* s = (const float4*)(w + (size_t)n * K + (size_t)c * 16);
  uint32_t x0 = pack4f_swz(s[0]), x1 = pack4f_swz(s[1]), x2 = pack4f_swz(s[2]), x3 = pack4f_swz(s[3]);
  *(uint4*)(out + ((size_t)c * N + n) * 16) = make_uint4(x0, x1, x2, x3);
}

__global__ __launch_bounds__(256) void zero_k(uint32_t* __restrict__ p, int n4) {
  int i = blockIdx.x * 256 + threadIdx.x;
  if (i < n4) ((uint4*)p)[i] = make_uint4(0u, 0u, 0u, 0u);
}

__global__ __launch_bounds__(256) void finalize_k(uint32_t* __restrict__ io,
                                                  const float* __restrict__ bias,
                                                  int n4, int N) {
  int i = blockIdx.x * 256 + threadIdx.x;
  if (i >= n4) return;
  uint4 v = ((const uint4*)io)[i];
  int base = (i * 4) % N;  // 4 consecutive elements stay within a row (N%4==0)
  float4 f;
  f.x = (float)v.x + bias[base + 0];
  f.y = (float)v.y + bias[base + 1];
  f.z = (float)v.z + bias[base + 2];
  f.w = (float)v.w + bias[base + 3];
  ((float4*)io)[i] = f;
}

// Main: per-wave packed T-table. Wave owns 8 rows x 512 cols x K/KSPLIT k.
// Per k: read 8 LUT rows (conflict-free ds_read_b32), v_perm transpose ->
// T[w] = 8 packed row-bytes (u64), then 1 ds_read_b64 per column serves 8 rows.
__global__ __launch_bounds__(512, 4) void lutmm_ttab(
    const uint8_t* __restrict__ A8,   // [M][K] u8 codes
    const uint8_t* __restrict__ WT,   // [K/16][N][16] u8, swizzled codes
    const uint8_t* __restrict__ LUT8, // [256][256] u8 linear
    uint32_t* __restrict__ out32,     // [M][N] u32, pre-zeroed
    int M, int N, int K) {
  __shared__ uint32_t lut32[16384];   // 64KB LUT
  __shared__ uint2 T2[8 * 256];       // 2KB per wave
  {
    const uint4* s = (const uint4*)LUT8;
    uint4* d = (uint4*)lut32;
#pragma unroll
    for (int i = 0; i < 8; i++) d[threadIdx.x + i * 512] = s[threadIdx.x + i * 512];
  }
  __syncthreads();

  const int lane = threadIdx.x & 63;
  const int wid  = threadIdx.x >> 6;
  const int r0   = blockIdx.y * 16 + (wid >> 2) * 8;   // wave's 8 rows
  const int cg   = (wid & 3) * 512;                    // wave's 512-col group
  const int k0   = blockIdx.x * (K / KSPLIT);
  const int kend = k0 + K / KSPLIT;
  uint2* Tw = &T2[wid * 256];

  uint32_t acc[8][4] = {};  // [col][rowpair-q]: u16 pairs, max 256*255 < 65536

  for (int kc = k0; kc < kend; kc += 8) {
    uint2 aw[8], wv[8];
#pragma unroll
    for (int j = 0; j < 8; j++)
      aw[j] = *(const uint2*)(A8 + (size_t)(r0 + j) * K + kc);   // wave-uniform
    const uint8_t* wtb = WT + ((size_t)(kc >> 4) * N) * 16 + (kc & 15);
#pragma unroll
    for (int c = 0; c < 8; c++)
      wv[c] = *(const uint2*)(wtb + (size_t)(cg + c * 64 + lane) * 16);  // coalesced

#pragma unroll
    for (int kk = 0; kk < 8; kk++) {
      const int sh = (kk & 3) * 8;
      uint32_t r_[8];
#pragma unroll
      for (int j = 0; j < 8; j++) {
        uint32_t a = (((kk < 4) ? aw[j].x : aw[j].y) >> sh) & 255u;
        r_[j] = lut32[(a << 6) + lane];   // full row across lanes: conflict-free
      }
      // byte-transpose: T entry w = 4*lane+p gets bytes {row0..row7}[w]
#pragma unroll
      for (int p = 0; p < 4; p++) {
        uint32_t selp = (uint32_t)p | ((uint32_t)(4 + p) << 8) |
                        ((uint32_t)p << 16) | ((uint32_t)(4 + p) << 24);
        uint32_t t01 = __builtin_amdgcn_perm(r_[1], r_[0], selp);
        uint32_t t23 = __builtin_amdgcn_perm(r_[3], r_[2], selp);
        uint32_t t45 = __builtin_amdgcn_perm(r_[5], r_[4], selp);
        uint32_t t67 = __builtin_amdgcn_perm(r_[7], r_[6], selp);
        uint32_t lo = __builtin_amdgcn_perm(t23, t01, 0x05040100u);
        uint32_t hi = __builtin_amdgcn_perm(t67, t45, 0x05040100u);
        Tw[lane | (p << 6)] = make_uint2(lo, hi);  // index = w' rotation: 2-way max on write
      }
      // gathers: one b64 per column serves all 8 rows
#pragma unroll
      for (int c = 0; c < 8; c++) {
        uint32_t wq = (((kk < 4) ? wv[c].x : wv[c].y) >> sh) & 255u;  // pre-swizzled w'
        uint2 g = Tw[wq];
        acc[c][0] += __builtin_amdgcn_perm(0u, g.x, 0x05010400u);  // rows 0,1 as u16 pair
        acc[c][1] += __builtin_amdgcn_perm(0u, g.x, 0x05030402u);  // rows 2,3
        acc[c][2] += __builtin_amdgcn_perm(0u, g.y, 0x05010400u);  // rows 4,5
        acc[c][3] += __builtin_amdgcn_perm(0u, g.y, 0x05030402u);  // rows 6,7
      }
    }
  }

#pragma unroll
  for (int c = 0; c < 8; c++) {
    int col = cg + c * 64 + lane;
#pragma unroll
    for (int q = 0; q < 4; q++) {
      uint32_t v = acc[c][q];
      atomicAdd(&out32[(size_t)(r0 + 2 * q) * N + col], v & 0xFFFFu);
      atomicAdd(&out32[(size_t)(r0 + 2 * q + 1) * N + col], v >> 16);
    }
  }
}

// Fallback if ws too small: direct f32 reads (R1-proven structure).
__global__ __launch_bounds__(1024, 8) void lutmm_f32(
    const float* __restrict__ A, const float* __restrict__ W,
    const int* __restrict__ LUT32, const float* __restrict__ bias,
    float* __restrict__ out, int M, int N, int K) {
  __shared__ uint8_t lut[65536];
  for (int i = threadIdx.x; i < 16384; i += 1024) {
    int4 v = ((const int4*)LUT32)[i];
    ((uint32_t*)lut)[i] = (uint32_t)(v.x & 255) | ((uint32_t)(v.y & 255) << 8) |
                          ((uint32_t)(v.z & 255) << 16) | ((uint32_t)(v.w & 255) << 24);
  }
  __syncthreads();

  const int lane = threadIdx.x & 63;
  const int wid = threadIdx.x >> 6;
  const int r0 = blockIdx.y * 16 + wid;
  const int cbase = blockIdx.x * 256 + lane;
  uint32_t acc[4] = {};

  for (int kb = 0; kb < K; kb += 16) {
    const float4* sa = (const float4*)(A + (size_t)r0 * K + kb);
    uint4 ap = make_uint4(pack4f(sa[0]), pack4f(sa[1]), pack4f(sa[2]), pack4f(sa[3]));
    uint4 wp[4];
#pragma unroll
    for (int j = 0; j < 4; j++) {
      const float4* s = (const float4*)(W + (size_t)(cbase + j * 64) * K + kb);
      wp[j] = make_uint4(pack4f(s[0]), pack4f(s[1]), pack4f(s[2]), pack4f(s[3]));
    }
#pragma unroll
    for (int q = 0; q < 4; q++)
#pragma unroll
      for (int b = 0; b < 4; b++) {
        uint32_t as = ((qword(ap, q) >> (b * 8)) & 255u) << 8;
#pragma unroll
        for (int j = 0; j < 4; j++)
          acc[j] += lut[as | ((qword(wp[j], q) >> (b * 8)) & 255u)];
      }
  }

#pragma unroll
  for (int j = 0; j < 4; j++) {
    int c = cbase + j * 64;
    out[(size_t)r0 * N + c] = (float)acc[j] + bias[c];
  }
}

extern "C" void kernel_launch(void* const* d_in, const int* in_sizes, int n_in,
                              void* d_out, int out_size, void* d_ws, size_t ws_size,
                              hipStream_t stream) {
  const float* inp  = (const float*)d_in[0];  // [M][K]
  const float* wgt  = (const float*)d_in[1];  // [N][K]
  const float* bias = (const float*)d_in[2];  // [N]
  const int*   lut  = (const int*)d_in[3];    // [256][256]

  const int N = in_sizes[2];
  const int K = in_sizes[1] / N;
  const int M = in_sizes[0] / K;

  size_t need = 65536 + (size_t)M * K + (size_t)N * K;

  if (ws_size >= need && (N % 2048) == 0 && (M % 16) == 0 && (K % (KSPLIT * 16)) == 0) {
    uint8_t* lut8 = (uint8_t*)d_ws;
    uint8_t* a8   = lut8 + 65536;           // [M][K]
    uint8_t* wt8  = a8 + (size_t)M * K;     // [K/16][N][16], swizzled codes
    pack_lut_k<<<16, 256, 0, stream>>>(lut, lut8, 65536 / 16);
    int an16 = (M * K) / 16;
    pack_lin_k<<<(an16 + 255) / 256, 256, 0, stream>>>(inp, a8, an16);
    int wn16 = (N * K) / 16;
    pack_wt_swz_k<<<(wn16 + 255) / 256, 256, 0, stream>>>(wgt, wt8, N, K);

    uint32_t* out32 = (uint32_t*)d_out;
    int n4 = (M * N) / 4;
    zero_k<<<(n4 + 255) / 256, 256, 0, stream>>>(out32, n4);
    dim3 grid(KSPLIT, M / 16);
    lutmm_ttab<<<grid, 512, 0, stream>>>(a8, wt8, lut8, out32, M, N, K);
    finalize_k<<<(n4 + 255) / 256, 256, 0, stream>>>(out32, bias, n4, N);
  } else {
    dim3 grid(N / 256, M / 16);
    lutmm_f32<<<grid, 1024, 0, stream>>>(inp, wgt, lut, bias, (float*)d_out, M, N, K);
  }
}